// Round 8
// baseline (228.777 us; speedup 1.0000x reference)
//
#include <hip/hip_runtime.h>
#include <hip/hip_bf16.h>
#include <cstdint>

// Problem constants: B=2, L=2048, D=1024, H=16, HD=64
#define LEN   2048
#define DMODEL 1024
#define NH    16
#define HD    64
#define BH    32          // B*NH
#define MROWS 4096        // B*LEN

typedef __attribute__((ext_vector_type(8))) short bf16x8;
typedef __attribute__((ext_vector_type(4))) float f32x4;
typedef __attribute__((ext_vector_type(16))) float f32x16;
typedef unsigned int u32;

__device__ __forceinline__ void gload_lds16(const void* g, void* l) {
    __builtin_amdgcn_global_load_lds(
        (const __attribute__((address_space(1))) u32*)g,
        (__attribute__((address_space(3))) u32*)l, 16, 0, 0);
}

__device__ __forceinline__ unsigned short bfb(float f) {
    __hip_bfloat16 h = __float2bfloat16(f);
    return *reinterpret_cast<unsigned short*>(&h);
}

__device__ __forceinline__ u32 pk2(float lo, float hi) {
    return (u32)bfb(lo) | ((u32)bfb(hi) << 16);
}

// ---------------------------------------------------------------- fused casts
__global__ void cast_all_k(const float* __restrict__ x,
                           const float* __restrict__ wq, const float* __restrict__ wk,
                           const float* __restrict__ wv, const float* __restrict__ wo,
                           __hip_bfloat16* __restrict__ x_bf,
                           __hip_bfloat16* __restrict__ wqkv,
                           __hip_bfloat16* __restrict__ wo_bf) {
    constexpr int XC = 1048576;          // x chunks (float4)
    constexpr int WC = 262144;           // per-weight chunks
    constexpr int TC = XC + 4 * WC;
    int stride = gridDim.x * blockDim.x;
    for (int i = blockIdx.x * blockDim.x + threadIdx.x; i < TC; i += stride) {
        const float* src; __hip_bfloat16* dst; int so, do_;
        if (i < XC) { src = x; dst = x_bf; so = i; do_ = i; }
        else {
            int j = i - XC, w = j >> 18, o = j & (WC - 1);
            src = w == 0 ? wq : (w == 1 ? wk : (w == 2 ? wv : wo));
            so = o;
            if (w < 3) { dst = wqkv; do_ = j; }
            else       { dst = wo_bf; do_ = o; }
        }
        float4 v = reinterpret_cast<const float4*>(src)[so];
        ushort4 p;
        p.x = bfb(v.x); p.y = bfb(v.y); p.z = bfb(v.z); p.w = bfb(v.w);
        reinterpret_cast<ushort4*>(dst)[do_] = p;
    }
}

// ---------------------------------------------------------------- fused QKV GEMM
__global__ __launch_bounds__(256) void gemm_qkv(
    const __hip_bfloat16* __restrict__ A,
    const __hip_bfloat16* __restrict__ Bw,
    const float* __restrict__ bq, const float* __restrict__ bk,
    const float* __restrict__ bv,
    __hip_bfloat16* __restrict__ Qb, __hip_bfloat16* __restrict__ Kb,
    __hip_bfloat16* __restrict__ VTb) {
    constexpr int Kd = DMODEL;
    __shared__ __hip_bfloat16 As[128 * 32];
    __shared__ __hip_bfloat16 Bs[128 * 32];
    const int lin = blockIdx.x;
    const int wg = (lin & 7) * 96 + (lin >> 3);   // bijective (768 = 8*96)
    const int by = wg / 24, bx = wg % 24;
    const int tid = threadIdx.x;
    const int wave = tid >> 6, lane = tid & 63;
    const int lg = lane >> 4, lr = lane & 15;
    const int wr = wave >> 1, wc = wave & 1;
    const __hip_bfloat16* Ab = A + (size_t)by * 128 * Kd;
    const __hip_bfloat16* Bb = Bw + (size_t)bx * 128 * Kd;
    f32x4 acc[4][4] = {};
    for (int kt = 0; kt < Kd / 32; ++kt) {
#pragma unroll
        for (int i = 0; i < 2; ++i) {
            int c = tid + i * 256;
            int row = c >> 2, c4 = c & 3;
            gload_lds16(Ab + (size_t)row * Kd + kt * 32 + c4 * 8, &As[c * 8]);
        }
#pragma unroll
        for (int i = 0; i < 2; ++i) {
            int c = tid + i * 256;
            int row = c >> 2, c4 = c & 3;
            gload_lds16(Bb + (size_t)row * Kd + kt * 32 + c4 * 8, &Bs[c * 8]);
        }
        __syncthreads();
        bf16x8 af[4], bfr[4];
#pragma unroll
        for (int m = 0; m < 4; ++m)
            af[m] = *(const bf16x8*)&As[(wr * 64 + m * 16 + lr) * 32 + lg * 8];
#pragma unroll
        for (int n = 0; n < 4; ++n)
            bfr[n] = *(const bf16x8*)&Bs[(wc * 64 + n * 16 + lr) * 32 + lg * 8];
        __builtin_amdgcn_s_setprio(1);
#pragma unroll
        for (int m = 0; m < 4; ++m)
#pragma unroll
            for (int n = 0; n < 4; ++n)
                acc[m][n] = __builtin_amdgcn_mfma_f32_16x16x32_bf16(
                    af[m], bfr[n], acc[m][n], 0, 0, 0);
        __builtin_amdgcn_s_setprio(0);
        __syncthreads();
    }
    const int sel = (bx * 128) >> 10;  // block-uniform 0/1/2
    const float* bp = sel == 0 ? bq : (sel == 1 ? bk : bv);
    __hip_bfloat16* dst = sel == 0 ? Qb : (sel == 1 ? Kb : VTb);
#pragma unroll
    for (int m = 0; m < 4; ++m)
#pragma unroll
        for (int n = 0; n < 4; ++n)
#pragma unroll
            for (int r = 0; r < 4; ++r) {
                int gm = by * 128 + wr * 64 + m * 16 + lg * 4 + r;
                int gn = bx * 128 + wc * 64 + n * 16 + lr;
                int nn = gn & (DMODEL - 1);
                float v = acc[m][n][r] + bp[nn];
                int bb = gm >> 11, l = gm & (LEN - 1);
                int h = nn >> 6, hd = nn & (HD - 1);
                size_t addr = (sel < 2)
                    ? ((((size_t)bb * NH + h) * LEN + l) * HD + hd)
                    : ((((size_t)bb * NH + h) * HD + hd) * LEN + l);
                dst[addr] = __float2bfloat16(v);
            }
}

// ---------------------------------------------------------------- flash attention
// grid 512 (XCD-swizzled), 4 waves x 32 q-rows = 128 q/block. KVBLK=64 dbuf LDS.
// 32x32x16 MFMA, swapped QK^T (lane: q=lane&31, 32 keys in s-regs).
// P hand-off via per-wave LDS (layout-agnostic); shuffles for cross-half combine.
#define SC 0.18033688f    // 0.125 * log2(e)
__global__ __launch_bounds__(256) void attn_fwd(
    const __hip_bfloat16* __restrict__ Qb,   // [BH][L][HD]
    const __hip_bfloat16* __restrict__ Kb,   // [BH][L][HD]
    const __hip_bfloat16* __restrict__ VTb,  // [BH][HD][L]
    __hip_bfloat16* __restrict__ Ob) {       // [B][L][D]
    const int lin = blockIdx.x;
    const int wg = (lin & 7) * 64 + (lin >> 3);   // bijective (512 = 8*64)
    const int bh = wg >> 4;          // 0..31
    const int qt = wg & 15;          // 0..15 (128-row q tiles)
    const int b = bh >> 4, h = bh & (NH - 1);
    const int tid = threadIdx.x;
    const int wave = tid >> 6, lane = tid & 63;
    const int l31 = lane & 31, hi = lane >> 5;
    const int qw = qt * 128 + wave * 32;
    const __hip_bfloat16* Qp = Qb + ((size_t)bh * LEN + qw) * HD;
    const __hip_bfloat16* Kp = Kb + (size_t)bh * LEN * HD;
    const __hip_bfloat16* Vp = VTb + (size_t)bh * HD * LEN;

    __shared__ __hip_bfloat16 Ks[2][64 * 64];
    __shared__ __hip_bfloat16 Vs[2][64 * 64];
    __shared__ __hip_bfloat16 Pl[4][32][72];   // per-wave P: [q][key], stride 72
    __hip_bfloat16* prow = &Pl[wave][l31][0];  // this lane's q-row

    // staging: 512 chunks of 16B per tile; each thread owns 2 K + 2 V chunks
    const int c0 = tid, c1 = tid + 256;
    const int r0 = c0 >> 3, j0 = (c0 & 7) ^ (r0 & 7);
    const int r1 = c1 >> 3, j1 = (c1 & 7) ^ (r1 & 7);
    const __hip_bfloat16* kg0 = Kp + (size_t)r0 * HD + j0 * 8;
    const __hip_bfloat16* kg1 = Kp + (size_t)r1 * HD + j1 * 8;
    const __hip_bfloat16* vg0 = Vp + (size_t)r0 * LEN + j0 * 8;
    const __hip_bfloat16* vg1 = Vp + (size_t)r1 * LEN + j1 * 8;

    // Q frags (B-operand, col q=l31, elem j <-> feature ks*16 + hi*8 + j)
    bf16x8 qf[4];
#pragma unroll
    for (int ks = 0; ks < 4; ++ks)
        qf[ks] = *(const bf16x8*)(Qp + l31 * HD + ks * 16 + hi * 8);

    float m_i = -INFINITY;   // per-lane scalar, q = l31, base-2 domain
    float l_i = 0.f;
    f32x16 o[2] = {};        // q = (r&3)+8*(r>>2)+4*hi, d = nd*32 + l31

    gload_lds16(kg0, &Ks[0][c0 * 8]);
    gload_lds16(kg1, &Ks[0][c1 * 8]);
    gload_lds16(vg0, &Vs[0][c0 * 8]);
    gload_lds16(vg1, &Vs[0][c1 * 8]);
    __syncthreads();

    const int swz = l31 & 7;
    constexpr int NT = LEN / 64;
    for (int kt = 0; kt < NT; ++kt) {
        const int cb = kt & 1, nb = cb ^ 1;
        if (kt + 1 < NT) {
            size_t ko = (size_t)(kt + 1) * 64 * HD;
            size_t vo = (size_t)(kt + 1) * 64;
            gload_lds16(kg0 + ko, &Ks[nb][c0 * 8]);
            gload_lds16(kg1 + ko, &Ks[nb][c1 * 8]);
            gload_lds16(vg0 + vo, &Vs[nb][c0 * 8]);
            gload_lds16(vg1 + vo, &Vs[nb][c1 * 8]);
        }
        const __hip_bfloat16* ksp = Ks[cb];
        const __hip_bfloat16* vsp = Vs[cb];
        // --- QK^T swapped (A=K, B=Q): s0/s1 reg r = score(key, q=l31),
        //     key = {0,32} + (r&3) + 8*(r>>2) + 4*hi
        f32x16 s0 = {}, s1 = {};
        __builtin_amdgcn_s_setprio(1);
#pragma unroll
        for (int ks = 0; ks < 4; ++ks) {
            int ch = ((ks << 1) + hi);
            bf16x8 kf0 = *(const bf16x8*)&ksp[l31 * 64 + (ch ^ swz) * 8];
            bf16x8 kf1 = *(const bf16x8*)&ksp[(32 + l31) * 64 + (ch ^ swz) * 8];
            s0 = __builtin_amdgcn_mfma_f32_32x32x16_bf16(kf0, qf[ks], s0, 0, 0, 0);
            s1 = __builtin_amdgcn_mfma_f32_32x32x16_bf16(kf1, qf[ks], s1, 0, 0, 0);
        }
        __builtin_amdgcn_s_setprio(0);
        // --- softmax: in-lane tree over 32 + cross-half shfl_xor ---
        float mx[16];
#pragma unroll
        for (int r = 0; r < 16; ++r) mx[r] = fmaxf(s0[r], s1[r]);
#pragma unroll
        for (int st = 8; st > 0; st >>= 1)
#pragma unroll
            for (int r = 0; r < 8; ++r)
                if (r < st) mx[r] = fmaxf(mx[r], mx[r + st]);
        float tmax = fmaxf(mx[0], __shfl_xor(mx[0], 32, 64));
        float pmax = tmax * SC;
        if (__any(pmax > m_i + 8.f)) {   // defer-max
            float mnew = fmaxf(m_i, pmax);
            float corr = exp2f(m_i - mnew);
            m_i = mnew;
            l_i *= corr;
#pragma unroll
            for (int r = 0; r < 16; ++r) {
                float cr = __shfl(corr, (r & 3) + 8 * (r >> 2) + 4 * hi, 32);
                o[0][r] *= cr;
                o[1][r] *= cr;
            }
        }
#pragma unroll
        for (int r = 0; r < 16; ++r) {
            s0[r] = exp2f(s0[r] * SC - m_i);
            s1[r] = exp2f(s1[r] * SC - m_i);
        }
        float sm[16];
#pragma unroll
        for (int r = 0; r < 16; ++r) sm[r] = s0[r] + s1[r];
#pragma unroll
        for (int st = 8; st > 0; st >>= 1)
#pragma unroll
            for (int r = 0; r < 8; ++r)
                if (r < st) sm[r] += sm[r + st];
        l_i += sm[0] + __shfl_xor(sm[0], 32, 64);
        // --- P -> per-wave LDS by (q,key): regs 4g..4g+3 = keys {0,32}+8g+4hi ---
#pragma unroll
        for (int g = 0; g < 4; ++g) {
            uint2 w0, w1;
            w0.x = pk2(s0[4 * g + 0], s0[4 * g + 1]);
            w0.y = pk2(s0[4 * g + 2], s0[4 * g + 3]);
            w1.x = pk2(s1[4 * g + 0], s1[4 * g + 1]);
            w1.y = pk2(s1[4 * g + 2], s1[4 * g + 3]);
            *(uint2*)&prow[8 * g + 4 * hi]      = w0;
            *(uint2*)&prow[32 + 8 * g + 4 * hi] = w1;
        }
        asm volatile("" ::: "memory");
        // --- pa[ks] = P[q=l31][keys ks*16 + hi*8 .. +7] (matches V element keys) ---
        bf16x8 pa[4];
#pragma unroll
        for (int ks = 0; ks < 4; ++ks)
            pa[ks] = *(const bf16x8*)&prow[ks * 16 + hi * 8];
        // --- PV: O[q][d] += P@V (A=P rows q, B=V^T rows d) ---
        __builtin_amdgcn_s_setprio(1);
#pragma unroll
        for (int ks = 0; ks < 4; ++ks) {
            int ch = ((ks << 1) + hi);
            bf16x8 vf0 = *(const bf16x8*)&vsp[l31 * 64 + (ch ^ swz) * 8];
            bf16x8 vf1 = *(const bf16x8*)&vsp[(32 + l31) * 64 + (ch ^ swz) * 8];
            o[0] = __builtin_amdgcn_mfma_f32_32x32x16_bf16(pa[ks], vf0, o[0], 0, 0, 0);
            o[1] = __builtin_amdgcn_mfma_f32_32x32x16_bf16(pa[ks], vf1, o[1], 0, 0, 0);
        }
        __builtin_amdgcn_s_setprio(0);
        __syncthreads();
    }
    // epilogue: broadcast l per q via width-32 shuffle, normalize, write
#pragma unroll
    for (int r = 0; r < 16; ++r) {
        int q = (r & 3) + 8 * (r >> 2) + 4 * hi;
        float inv = 1.f / __shfl(l_i, q, 32);
        int gq = qw + q;
        size_t base = ((size_t)b * LEN + gq) * DMODEL + h * HD + l31;
        Ob[base]      = __float2bfloat16(o[0][r] * inv);
        Ob[base + 32] = __float2bfloat16(o[1][r] * inv);
    }
}

// ---------------------------------------------------------------- output GEMM
__global__ __launch_bounds__(256) void gemm_out(
    const __hip_bfloat16* __restrict__ A,    // [4096][1024]
    const __hip_bfloat16* __restrict__ Bw,   // [1024][1024]
    const float* __restrict__ bo, float* __restrict__ out) {
    constexpr int Kd = DMODEL, N = DMODEL;
    __shared__ __hip_bfloat16 As[128 * 32];
    __shared__ __hip_bfloat16 Bs[128 * 32];
    const int lin = blockIdx.x;
    const int wg = (lin & 7) * 32 + (lin >> 3);   // bijective (256 = 8*32)
    const int by = wg >> 3, bx = wg & 7;
    const int tid = threadIdx.x;
    const int wave = tid >> 6, lane = tid & 63;
    const int lg = lane >> 4, lr = lane & 15;
    const int wr = wave >> 1, wc = wave & 1;
    const __hip_bfloat16* Ab = A + (size_t)by * 128 * Kd;
    const __hip_bfloat16* Bb = Bw + (size_t)bx * 128 * Kd;
    f32x4 acc[4][4] = {};
    for (int kt = 0; kt < Kd / 32; ++kt) {
#pragma unroll
        for (int i = 0; i < 2; ++i) {
            int c = tid + i * 256;
            int row = c >> 2, c4 = c & 3;
            gload_lds16(Ab + (size_t)row * Kd + kt * 32 + c4 * 8, &As[c * 8]);
        }
#pragma unroll
        for (int i = 0; i < 2; ++i) {
            int c = tid + i * 256;
            int row = c >> 2, c4 = c & 3;
            gload_lds16(Bb + (size_t)row * Kd + kt * 32 + c4 * 8, &Bs[c * 8]);
        }
        __syncthreads();
        bf16x8 af[4], bfr[4];
#pragma unroll
        for (int m = 0; m < 4; ++m)
            af[m] = *(const bf16x8*)&As[(wr * 64 + m * 16 + lr) * 32 + lg * 8];
#pragma unroll
        for (int n = 0; n < 4; ++n)
            bfr[n] = *(const bf16x8*)&Bs[(wc * 64 + n * 16 + lr) * 32 + lg * 8];
        __builtin_amdgcn_s_setprio(1);
#pragma unroll
        for (int m = 0; m < 4; ++m)
#pragma unroll
            for (int n = 0; n < 4; ++n)
                acc[m][n] = __builtin_amdgcn_mfma_f32_16x16x32_bf16(
                    af[m], bfr[n], acc[m][n], 0, 0, 0);
        __builtin_amdgcn_s_setprio(0);
        __syncthreads();
    }
#pragma unroll
    for (int m = 0; m < 4; ++m)
#pragma unroll
        for (int n = 0; n < 4; ++n)
#pragma unroll
            for (int r = 0; r < 4; ++r) {
                int gm = by * 128 + wr * 64 + m * 16 + lg * 4 + r;
                int gn = bx * 128 + wc * 64 + n * 16 + lr;
                out[(size_t)gm * N + gn] = acc[m][n][r] + bo[gn];
            }
}

// ---------------------------------------------------------------- launch
extern "C" void kernel_launch(void* const* d_in, const int* in_sizes, int n_in,
                              void* d_out, int out_size, void* d_ws, size_t ws_size,
                              hipStream_t stream) {
    const float* x  = (const float*)d_in[0];
    const float* wq = (const float*)d_in[1];
    const float* bq = (const float*)d_in[2];
    const float* wk = (const float*)d_in[3];
    const float* bk = (const float*)d_in[4];
    const float* wv = (const float*)d_in[5];
    const float* bv = (const float*)d_in[6];
    const float* wo = (const float*)d_in[7];
    const float* bo = (const float*)d_in[8];

    char* ws = (char*)d_ws;
    __hip_bfloat16* x_bf  = (__hip_bfloat16*)(ws);                    // 8 MB
    __hip_bfloat16* wqkv  = (__hip_bfloat16*)(ws + (8u  << 20));      // 6 MB
    __hip_bfloat16* wo_bf = (__hip_bfloat16*)(ws + (14u << 20));      // 2 MB
    __hip_bfloat16* Qb    = (__hip_bfloat16*)(ws + (16u << 20));      // 8 MB
    __hip_bfloat16* Kb    = (__hip_bfloat16*)(ws + (24u << 20));      // 8 MB
    __hip_bfloat16* VTb   = (__hip_bfloat16*)(ws + (32u << 20));      // 8 MB
    __hip_bfloat16* Ob    = (__hip_bfloat16*)(ws + (40u << 20));      // 8 MB

    cast_all_k<<<1024, 256, 0, stream>>>(x, wq, wk, wv, wo, x_bf, wqkv, wo_bf);
    gemm_qkv<<<768, 256, 0, stream>>>(x_bf, wqkv, bq, bk, bv, Qb, Kb, VTb);
    attn_fwd<<<512, 256, 0, stream>>>(Qb, Kb, VTb, Ob);
    gemm_out<<<256, 256, 0, stream>>>(Ob, wo_bf, bo, (float*)d_out);
}

// Round 10
// 223.477 us; speedup vs baseline: 1.0237x; 1.0237x over previous
//
#include <hip/hip_runtime.h>
#include <hip/hip_bf16.h>
#include <cstdint>

// Problem constants: B=2, L=2048, D=1024, H=16, HD=64
#define LEN   2048
#define DMODEL 1024
#define NH    16
#define HD    64
#define BH    32          // B*NH
#define MROWS 4096        // B*LEN

typedef __attribute__((ext_vector_type(8))) short bf16x8;
typedef __attribute__((ext_vector_type(4))) float f32x4;
typedef __attribute__((ext_vector_type(16))) float f32x16;
typedef unsigned int u32;

__device__ __forceinline__ void gload_lds16(const void* g, void* l) {
    __builtin_amdgcn_global_load_lds(
        (const __attribute__((address_space(1))) u32*)g,
        (__attribute__((address_space(3))) u32*)l, 16, 0, 0);
}

__device__ __forceinline__ unsigned short bfb(float f) {
    __hip_bfloat16 h = __float2bfloat16(f);
    return *reinterpret_cast<unsigned short*>(&h);
}

__device__ __forceinline__ u32 pk2(float lo, float hi) {
    return (u32)bfb(lo) | ((u32)bfb(hi) << 16);
}

// ---------------------------------------------------------------- fused casts
__global__ void cast_all_k(const float* __restrict__ x,
                           const float* __restrict__ wq, const float* __restrict__ wk,
                           const float* __restrict__ wv, const float* __restrict__ wo,
                           __hip_bfloat16* __restrict__ x_bf,
                           __hip_bfloat16* __restrict__ wqkv,
                           __hip_bfloat16* __restrict__ wo_bf) {
    constexpr int XC = 1048576;          // x chunks (float4)
    constexpr int WC = 262144;           // per-weight chunks
    constexpr int TC = XC + 4 * WC;
    int stride = gridDim.x * blockDim.x;
    for (int i = blockIdx.x * blockDim.x + threadIdx.x; i < TC; i += stride) {
        const float* src; __hip_bfloat16* dst; int so, do_;
        if (i < XC) { src = x; dst = x_bf; so = i; do_ = i; }
        else {
            int j = i - XC, w = j >> 18, o = j & (WC - 1);
            src = w == 0 ? wq : (w == 1 ? wk : (w == 2 ? wv : wo));
            so = o;
            if (w < 3) { dst = wqkv; do_ = j; }
            else       { dst = wo_bf; do_ = o; }
        }
        float4 v = reinterpret_cast<const float4*>(src)[so];
        ushort4 p;
        p.x = bfb(v.x); p.y = bfb(v.y); p.z = bfb(v.z); p.w = bfb(v.w);
        reinterpret_cast<ushort4*>(dst)[do_] = p;
    }
}

// ---------------------------------------------------------------- fused QKV GEMM
// 128x128 tile, BK=32, double-buffered LDS staging (T3-min: prefetch -> compute
// -> single barrier per iter).
__global__ __launch_bounds__(256) void gemm_qkv(
    const __hip_bfloat16* __restrict__ A,
    const __hip_bfloat16* __restrict__ Bw,
    const float* __restrict__ bq, const float* __restrict__ bk,
    const float* __restrict__ bv,
    __hip_bfloat16* __restrict__ Qb, __hip_bfloat16* __restrict__ Kb,
    __hip_bfloat16* __restrict__ VTb) {
    constexpr int Kd = DMODEL;
    __shared__ __hip_bfloat16 As[2][128 * 32];
    __shared__ __hip_bfloat16 Bs[2][128 * 32];
    const int lin = blockIdx.x;
    const int wg = (lin & 7) * 96 + (lin >> 3);   // bijective (768 = 8*96)
    const int by = wg / 24, bx = wg % 24;
    const int tid = threadIdx.x;
    const int wave = tid >> 6, lane = tid & 63;
    const int lg = lane >> 4, lr = lane & 15;
    const int wr = wave >> 1, wc = wave & 1;
    const __hip_bfloat16* Ab = A + (size_t)by * 128 * Kd;
    const __hip_bfloat16* Bb = Bw + (size_t)bx * 128 * Kd;
    const int c0 = tid, c1 = tid + 256;
    const int ra0 = c0 >> 2, ca0 = c0 & 3;
    const int ra1 = c1 >> 2, ca1 = c1 & 3;
    f32x4 acc[4][4] = {};
    // prologue: stage kt=0 into buf 0
    gload_lds16(Ab + (size_t)ra0 * Kd + ca0 * 8, &As[0][c0 * 8]);
    gload_lds16(Ab + (size_t)ra1 * Kd + ca1 * 8, &As[0][c1 * 8]);
    gload_lds16(Bb + (size_t)ra0 * Kd + ca0 * 8, &Bs[0][c0 * 8]);
    gload_lds16(Bb + (size_t)ra1 * Kd + ca1 * 8, &Bs[0][c1 * 8]);
    __syncthreads();
    for (int kt = 0; kt < Kd / 32; ++kt) {
        const int cb = kt & 1, nb = cb ^ 1;
        if (kt + 1 < Kd / 32) {
            int ko = (kt + 1) * 32;
            gload_lds16(Ab + (size_t)ra0 * Kd + ko + ca0 * 8, &As[nb][c0 * 8]);
            gload_lds16(Ab + (size_t)ra1 * Kd + ko + ca1 * 8, &As[nb][c1 * 8]);
            gload_lds16(Bb + (size_t)ra0 * Kd + ko + ca0 * 8, &Bs[nb][c0 * 8]);
            gload_lds16(Bb + (size_t)ra1 * Kd + ko + ca1 * 8, &Bs[nb][c1 * 8]);
        }
        bf16x8 af[4], bfr[4];
#pragma unroll
        for (int m = 0; m < 4; ++m)
            af[m] = *(const bf16x8*)&As[cb][(wr * 64 + m * 16 + lr) * 32 + lg * 8];
#pragma unroll
        for (int n = 0; n < 4; ++n)
            bfr[n] = *(const bf16x8*)&Bs[cb][(wc * 64 + n * 16 + lr) * 32 + lg * 8];
        __builtin_amdgcn_s_setprio(1);
#pragma unroll
        for (int m = 0; m < 4; ++m)
#pragma unroll
            for (int n = 0; n < 4; ++n)
                acc[m][n] = __builtin_amdgcn_mfma_f32_16x16x32_bf16(
                    af[m], bfr[n], acc[m][n], 0, 0, 0);
        __builtin_amdgcn_s_setprio(0);
        __syncthreads();   // drains prefetch; nb ready for next iter
    }
    const int sel = (bx * 128) >> 10;  // block-uniform 0/1/2
    const float* bp = sel == 0 ? bq : (sel == 1 ? bk : bv);
    __hip_bfloat16* dst = sel == 0 ? Qb : (sel == 1 ? Kb : VTb);
#pragma unroll
    for (int m = 0; m < 4; ++m)
#pragma unroll
        for (int n = 0; n < 4; ++n)
#pragma unroll
            for (int r = 0; r < 4; ++r) {
                int gm = by * 128 + wr * 64 + m * 16 + lg * 4 + r;
                int gn = bx * 128 + wc * 64 + n * 16 + lr;
                int nn = gn & (DMODEL - 1);
                float v = acc[m][n][r] + bp[nn];
                int bb = gm >> 11, l = gm & (LEN - 1);
                int h = nn >> 6, hd = nn & (HD - 1);
                size_t addr = (sel < 2)
                    ? ((((size_t)bb * NH + h) * LEN + l) * HD + hd)
                    : ((((size_t)bb * NH + h) * HD + hd) * LEN + l);
                dst[addr] = __float2bfloat16(v);
            }
}

// ---------------------------------------------------------------- flash attention
// grid 512 (XCD-swizzled) x 512 threads: 8 waves = 4 q-strips x 2 key-halves.
// Wave: 32 q-rows x its 32-key half per 64-key tile, independent online softmax;
// epilogue merges the two key-half partials per strip (flash split-K merge).
#define SC 0.18033688f    // 0.125 * log2(e)
__global__ __launch_bounds__(512) void attn_fwd(
    const __hip_bfloat16* __restrict__ Qb,   // [BH][L][HD]
    const __hip_bfloat16* __restrict__ Kb,   // [BH][L][HD]
    const __hip_bfloat16* __restrict__ VTb,  // [BH][HD][L]
    __hip_bfloat16* __restrict__ Ob) {       // [B][L][D]
    const int lin = blockIdx.x;
    const int wg = (lin & 7) * 64 + (lin >> 3);   // bijective (512 = 8*64)
    const int bh = wg >> 4;          // 0..31
    const int qt = wg & 15;          // 0..15 (128-row q tiles)
    const int b = bh >> 4, h = bh & (NH - 1);
    const int tid = threadIdx.x;
    const int wave = tid >> 6, lane = tid & 63;
    const int l31 = lane & 31, hi = lane >> 5;
    const int strip = wave >> 1, kh = wave & 1;
    const int qw = qt * 128 + strip * 32;
    const __hip_bfloat16* Qp = Qb + ((size_t)bh * LEN + qw) * HD;
    const __hip_bfloat16* Kp = Kb + (size_t)bh * LEN * HD;
    const __hip_bfloat16* Vp = VTb + (size_t)bh * HD * LEN;

    // LDS pool: loop phase: Ks 16K | Vs 16K | Pl 20K; epilogue: MO 33K | ML 2K
    __shared__ alignas(16) char smem[53248];
    __hip_bfloat16* KsB = (__hip_bfloat16*)smem;              // [2][64*64]
    __hip_bfloat16* VsB = (__hip_bfloat16*)(smem + 16384);    // [2][64*64]
    __hip_bfloat16* PlB = (__hip_bfloat16*)(smem + 32768);    // [8][32][40]
    __hip_bfloat16* prow = PlB + (wave * 32 + l31) * 40;

    // staging: 512 chunks of 16B per tile; each thread owns 1 K + 1 V chunk
    const int c0 = tid;
    const int r0 = c0 >> 3, j0 = (c0 & 7) ^ (r0 & 7);
    const __hip_bfloat16* kg0 = Kp + (size_t)r0 * HD + j0 * 8;
    const __hip_bfloat16* vg0 = Vp + (size_t)r0 * LEN + j0 * 8;

    // Q frags (B-operand, col q=l31, elems = features ks*16 + hi*8 ..+7)
    bf16x8 qf[4];
#pragma unroll
    for (int ks = 0; ks < 4; ++ks)
        qf[ks] = *(const bf16x8*)(Qp + l31 * HD + ks * 16 + hi * 8);

    float m_i = -INFINITY;   // per-lane, q=l31, over THIS wave's key-half (base-2)
    float l_i = 0.f;
    f32x16 o0 = {}, o1 = {};   // q=(r&3)+8*(r>>2)+4*hi, d = {l31, 32+l31}

    gload_lds16(kg0, &KsB[c0 * 8]);
    gload_lds16(vg0, &VsB[c0 * 8]);
    __syncthreads();

    const int swz = l31 & 7;
    constexpr int NT = LEN / 64;
    for (int kt = 0; kt < NT; ++kt) {
        const int cb = kt & 1, nb = cb ^ 1;
        if (kt + 1 < NT) {
            gload_lds16(kg0 + (size_t)(kt + 1) * 64 * HD, &KsB[nb * 4096 + c0 * 8]);
            gload_lds16(vg0 + (size_t)(kt + 1) * 64,      &VsB[nb * 4096 + c0 * 8]);
        }
        const __hip_bfloat16* ksp = KsB + cb * 4096;
        const __hip_bfloat16* vsp = VsB + cb * 4096;
        // --- QK^T swapped (A=K rows key, B=Q): s reg r = score(key_local, q=l31),
        //     key_local = (r&3)+8*(r>>2)+4*hi  (within this wave's 32-key half)
        f32x16 s = {};
        __builtin_amdgcn_s_setprio(1);
#pragma unroll
        for (int ks = 0; ks < 4; ++ks) {
            int ch = (ks << 1) + hi;
            bf16x8 kf = *(const bf16x8*)&ksp[(kh * 32 + l31) * 64 + ((ch ^ swz)) * 8];
            s = __builtin_amdgcn_mfma_f32_32x32x16_bf16(kf, qf[ks], s, 0, 0, 0);
        }
        __builtin_amdgcn_s_setprio(0);
        // --- softmax over this 32-key half: in-lane tree + cross-half shfl ---
        float mx[16];
#pragma unroll
        for (int r = 0; r < 16; ++r) mx[r] = s[r];
#pragma unroll
        for (int st = 8; st > 0; st >>= 1)
#pragma unroll
            for (int r = 0; r < 8; ++r)
                if (r < st) mx[r] = fmaxf(mx[r], mx[r + st]);
        float tmax = fmaxf(mx[0], __shfl_xor(mx[0], 32, 64));
        float pmax = tmax * SC;
        if (__any(pmax > m_i + 8.f)) {   // defer-max
            float mnew = fmaxf(m_i, pmax);
            float corr = exp2f(m_i - mnew);
            m_i = mnew;
            l_i *= corr;
#pragma unroll
            for (int r = 0; r < 16; ++r) {
                float cr = __shfl(corr, (r & 3) + 8 * (r >> 2) + 4 * hi, 32);
                o0[r] *= cr;
                o1[r] *= cr;
            }
        }
#pragma unroll
        for (int r = 0; r < 16; ++r) s[r] = exp2f(s[r] * SC - m_i);
        float sm[16];
#pragma unroll
        for (int r = 0; r < 16; ++r) sm[r] = s[r];
#pragma unroll
        for (int st = 8; st > 0; st >>= 1)
#pragma unroll
            for (int r = 0; r < 8; ++r)
                if (r < st) sm[r] += sm[r + st];
        l_i += sm[0] + __shfl_xor(sm[0], 32, 64);
        // --- P -> per-wave LDS: row q=l31, col key_local (stride 40) ---
#pragma unroll
        for (int g = 0; g < 4; ++g) {
            uint2 w;
            w.x = pk2(s[4 * g + 0], s[4 * g + 1]);
            w.y = pk2(s[4 * g + 2], s[4 * g + 3]);
            *(uint2*)&prow[8 * g + 4 * hi] = w;
        }
        asm volatile("" ::: "memory");
        bf16x8 pa0 = *(const bf16x8*)&prow[hi * 8];
        bf16x8 pa1 = *(const bf16x8*)&prow[16 + hi * 8];
        // --- PV: O += P@V over this key-half (V chunks kh*4 + ks2*2 + hi) ---
        __builtin_amdgcn_s_setprio(1);
#pragma unroll
        for (int ks2 = 0; ks2 < 2; ++ks2) {
            int ch = kh * 4 + (ks2 << 1) + hi;
            bf16x8 pa = ks2 == 0 ? pa0 : pa1;
            bf16x8 vf0 = *(const bf16x8*)&vsp[l31 * 64 + ((ch ^ swz)) * 8];
            bf16x8 vf1 = *(const bf16x8*)&vsp[(32 + l31) * 64 + ((ch ^ swz)) * 8];
            o0 = __builtin_amdgcn_mfma_f32_32x32x16_bf16(pa, vf0, o0, 0, 0, 0);
            o1 = __builtin_amdgcn_mfma_f32_32x32x16_bf16(pa, vf1, o1, 0, 0, 0);
        }
        __builtin_amdgcn_s_setprio(0);
        __syncthreads();
    }
    // ---- epilogue: merge the two key-half partials per strip ----
    float* MO = (float*)smem;             // [4][64][33] f32 (pad 33: conflict-free)
    float* ML = (float*)(smem + 34816);   // [4][2][32][2] (m,l by l31)
    ML[((strip * 2 + kh) * 32 + l31) * 2 + 0] = m_i;
    ML[((strip * 2 + kh) * 32 + l31) * 2 + 1] = l_i;
    __syncthreads();
    float w_own[16], w_inv[16];
#pragma unroll
    for (int r = 0; r < 16; ++r) {
        int q = (r & 3) + 8 * (r >> 2) + 4 * hi;
        float m0 = ML[((strip * 2 + 0) * 32 + q) * 2 + 0];
        float l0 = ML[((strip * 2 + 0) * 32 + q) * 2 + 1];
        float m1 = ML[((strip * 2 + 1) * 32 + q) * 2 + 0];
        float l1 = ML[((strip * 2 + 1) * 32 + q) * 2 + 1];
        float m = fmaxf(m0, m1);
        float w0 = exp2f(m0 - m), w1 = exp2f(m1 - m);
        w_own[r] = (kh == 0) ? w0 : w1;
        w_inv[r] = 1.f / (l0 * w0 + l1 * w1);
    }
    if (kh == 1) {
#pragma unroll
        for (int r = 0; r < 16; ++r) {
            MO[(strip * 64 + lane) * 33 + r]      = o0[r] * w_own[r];
            MO[(strip * 64 + lane) * 33 + 16 + r] = o1[r] * w_own[r];
        }
    }
    __syncthreads();
    if (kh == 0) {
#pragma unroll
        for (int r = 0; r < 16; ++r) {
            int q = (r & 3) + 8 * (r >> 2) + 4 * hi;
            int gq = qw + q;
            size_t base = ((size_t)b * LEN + gq) * DMODEL + h * HD + l31;
            float v0 = (o0[r] * w_own[r] + MO[(strip * 64 + lane) * 33 + r]) * w_inv[r];
            float v1 = (o1[r] * w_own[r] + MO[(strip * 64 + lane) * 33 + 16 + r]) * w_inv[r];
            Ob[base]      = __float2bfloat16(v0);
            Ob[base + 32] = __float2bfloat16(v1);
        }
    }
}

// ---------------------------------------------------------------- output GEMM
// 128x128 tile, double-buffered staging, grid 256 XCD-swizzled.
__global__ __launch_bounds__(256) void gemm_out(
    const __hip_bfloat16* __restrict__ A,    // [4096][1024]
    const __hip_bfloat16* __restrict__ Bw,   // [1024][1024]
    const float* __restrict__ bo, float* __restrict__ out) {
    constexpr int Kd = DMODEL, N = DMODEL;
    __shared__ __hip_bfloat16 As[2][128 * 32];
    __shared__ __hip_bfloat16 Bs[2][128 * 32];
    const int lin = blockIdx.x;
    const int wg = (lin & 7) * 32 + (lin >> 3);   // bijective (256 = 8*32)
    const int by = wg >> 3, bx = wg & 7;
    const int tid = threadIdx.x;
    const int wave = tid >> 6, lane = tid & 63;
    const int lg = lane >> 4, lr = lane & 15;
    const int wr = wave >> 1, wc = wave & 1;
    const __hip_bfloat16* Ab = A + (size_t)by * 128 * Kd;
    const __hip_bfloat16* Bb = Bw + (size_t)bx * 128 * Kd;
    const int c0 = tid, c1 = tid + 256;
    const int ra0 = c0 >> 2, ca0 = c0 & 3;
    const int ra1 = c1 >> 2, ca1 = c1 & 3;
    f32x4 acc[4][4] = {};
    gload_lds16(Ab + (size_t)ra0 * Kd + ca0 * 8, &As[0][c0 * 8]);
    gload_lds16(Ab + (size_t)ra1 * Kd + ca1 * 8, &As[0][c1 * 8]);
    gload_lds16(Bb + (size_t)ra0 * Kd + ca0 * 8, &Bs[0][c0 * 8]);
    gload_lds16(Bb + (size_t)ra1 * Kd + ca1 * 8, &Bs[0][c1 * 8]);
    __syncthreads();
    for (int kt = 0; kt < Kd / 32; ++kt) {
        const int cb = kt & 1, nb = cb ^ 1;
        if (kt + 1 < Kd / 32) {
            int ko = (kt + 1) * 32;
            gload_lds16(Ab + (size_t)ra0 * Kd + ko + ca0 * 8, &As[nb][c0 * 8]);
            gload_lds16(Ab + (size_t)ra1 * Kd + ko + ca1 * 8, &As[nb][c1 * 8]);
            gload_lds16(Bb + (size_t)ra0 * Kd + ko + ca0 * 8, &Bs[nb][c0 * 8]);
            gload_lds16(Bb + (size_t)ra1 * Kd + ko + ca1 * 8, &Bs[nb][c1 * 8]);
        }
        bf16x8 af[4], bfr[4];
#pragma unroll
        for (int m = 0; m < 4; ++m)
            af[m] = *(const bf16x8*)&As[cb][(wr * 64 + m * 16 + lr) * 32 + lg * 8];
#pragma unroll
        for (int n = 0; n < 4; ++n)
            bfr[n] = *(const bf16x8*)&Bs[cb][(wc * 64 + n * 16 + lr) * 32 + lg * 8];
        __builtin_amdgcn_s_setprio(1);
#pragma unroll
        for (int m = 0; m < 4; ++m)
#pragma unroll
            for (int n = 0; n < 4; ++n)
                acc[m][n] = __builtin_amdgcn_mfma_f32_16x16x32_bf16(
                    af[m], bfr[n], acc[m][n], 0, 0, 0);
        __builtin_amdgcn_s_setprio(0);
        __syncthreads();
    }
#pragma unroll
    for (int m = 0; m < 4; ++m)
#pragma unroll
        for (int n = 0; n < 4; ++n)
#pragma unroll
            for (int r = 0; r < 4; ++r) {
                int gm = by * 128 + wr * 64 + m * 16 + lg * 4 + r;
                int gn = bx * 128 + wc * 64 + n * 16 + lr;
                out[(size_t)gm * N + gn] = acc[m][n][r] + bo[gn];
            }
}

// ---------------------------------------------------------------- launch
extern "C" void kernel_launch(void* const* d_in, const int* in_sizes, int n_in,
                              void* d_out, int out_size, void* d_ws, size_t ws_size,
                              hipStream_t stream) {
    const float* x  = (const float*)d_in[0];
    const float* wq = (const float*)d_in[1];
    const float* bq = (const float*)d_in[2];
    const float* wk = (const float*)d_in[3];
    const float* bk = (const float*)d_in[4];
    const float* wv = (const float*)d_in[5];
    const float* bv = (const float*)d_in[6];
    const float* wo = (const float*)d_in[7];
    const float* bo = (const float*)d_in[8];

    char* ws = (char*)d_ws;
    __hip_bfloat16* x_bf  = (__hip_bfloat16*)(ws);                    // 8 MB
    __hip_bfloat16* wqkv  = (__hip_bfloat16*)(ws + (8u  << 20));      // 6 MB
    __hip_bfloat16* wo_bf = (__hip_bfloat16*)(ws + (14u << 20));      // 2 MB
    __hip_bfloat16* Qb    = (__hip_bfloat16*)(ws + (16u << 20));      // 8 MB
    __hip_bfloat16* Kb    = (__hip_bfloat16*)(ws + (24u << 20));      // 8 MB
    __hip_bfloat16* VTb   = (__hip_bfloat16*)(ws + (32u << 20));      // 8 MB
    __hip_bfloat16* Ob    = (__hip_bfloat16*)(ws + (40u << 20));      // 8 MB

    cast_all_k<<<1024, 256, 0, stream>>>(x, wq, wk, wv, wo, x_bf, wqkv, wo_bf);
    gemm_qkv<<<768, 256, 0, stream>>>(x_bf, wqkv, bq, bk, bv, Qb, Kb, VTb);
    attn_fwd<<<512, 512, 0, stream>>>(Qb, Kb, VTb, Ob);
    gemm_out<<<256, 256, 0, stream>>>(Ob, wo_bf, bo, (float*)d_out);
}